// Round 18
// baseline (228.629 us; speedup 1.0000x reference)
//
#include <hip/hip_runtime.h>
#include <stdint.h>

#define NB 4
#define NC 256
#define NH 60
#define NW 80
#define NN (NH*NW)   // 4800

#define M_POS 1.0f
#define M_NEG 0.2f
#define THR2  64.0f  // THRESHOLD^2

typedef __attribute__((ext_vector_type(4))) float f32x4;
typedef __attribute__((ext_vector_type(8))) int   i32x8;
typedef __attribute__((ext_vector_type(4))) int   i32x4v;

#define SC1 0x7F7F7F7F   // e8m0 scale bytes = 127 -> 2^0 = 1.0

// ws layout (bytes):
//      0 : gemmbuf[6000] float
//  24000 : corrbuf[1200] float     (contiguous: NPART = 7200 floats from 0)
//  28800 : done-counter (uint32, memsetAsync'd to 0 each call)
// 102400 : A8 [B][N][C] fp8 e4m3   (4915200 B)
// 5017600: B8 [B][N][C] fp8 e4m3   (4915200 B)
#define CORR_OFF 24000
#define CNT_OFF  28800
#define A8_OFF   102400
#define B8_OFF   5017600
#define NPART    7200

#define NGEMM 6000
#define NCORR 1200
#define NBLK  (NGEMM + NCORR)

// ---------------- transpose+convert [C][N] f32 -> [N][C] fp8 ----------------
__global__ void t8_kernel(const float* __restrict__ da, const float* __restrict__ db,
                          unsigned char* __restrict__ A8, unsigned char* __restrict__ B8) {
  int t = blockIdx.x;              // 0..2399 = 2 tensors * 4 b * 4 ct * 75 nt
  int tensor = t / 1200; int rem = t % 1200;
  int b  = rem / 300;    int rem2 = rem % 300;
  int ct = rem2 / 75,    nt = rem2 % 75;
  int c0 = ct * 64, n0 = nt * 64;
  const float* in = (tensor ? db : da) + ((size_t)b * NC + c0) * NN + n0;
  unsigned char* out = (tensor ? B8 : A8) + ((size_t)b * NN + n0) * NC + c0;

  __shared__ float tile[64][65];
  int tr = threadIdx.x >> 6, tc = threadIdx.x & 63;
  #pragma unroll
  for (int i = 0; i < 16; ++i) {
    int c = i * 4 + tr;
    tile[c][tc] = in[(size_t)c * NN + tc];
  }
  __syncthreads();
  // each thread: one n-row, 16 consecutive channels -> one uint4 store
  int n_loc = threadIdx.x >> 2;        // 0..63
  int cb    = (threadIdx.x & 3) * 16;  // 0,16,32,48
  uint32_t wv[4];
  #pragma unroll
  for (int q = 0; q < 4; ++q) {
    uint32_t r = 0;
    r = __builtin_amdgcn_cvt_pk_fp8_f32(tile[cb + q*4 + 0][n_loc], tile[cb + q*4 + 1][n_loc], r, 0);
    r = __builtin_amdgcn_cvt_pk_fp8_f32(tile[cb + q*4 + 2][n_loc], tile[cb + q*4 + 3][n_loc], r, 1);
    wv[q] = r;
  }
  uint4 pack = make_uint4(wv[0], wv[1], wv[2], wv[3]);
  *(uint4*)&out[(size_t)n_loc * NC + cb] = pack;
}

__device__ __forceinline__ float dot16(uint32_t a, uint32_t b, float acc) {
  acc += __builtin_amdgcn_cvt_f32_fp8(a, 0) * __builtin_amdgcn_cvt_f32_fp8(b, 0);
  acc += __builtin_amdgcn_cvt_f32_fp8(a, 1) * __builtin_amdgcn_cvt_f32_fp8(b, 1);
  acc += __builtin_amdgcn_cvt_f32_fp8(a, 2) * __builtin_amdgcn_cvt_f32_fp8(b, 2);
  acc += __builtin_amdgcn_cvt_f32_fp8(a, 3) * __builtin_amdgcn_cvt_f32_fp8(b, 3);
  return acc;
}

// ---------------- fused MX-fp8 GEMM(+hinge) + corr + final-reduce kernel ----
// blocks [0,6000): GEMM 160(n)x96(m) (R14-exact memory system/schedule).
// blocks [6000,7200): sparse mask correction, 16 lanes per (b,n) item.
// LAST block to finish (device-scope counter) reduces all 7200 partials
// and writes the mean to d_out -- no separate finalize dispatch.
#define BM 160
#define BN 96
#define BK 64

#define STAGE(t, p, LA, LB) do {                                                      \
    _Pragma("unroll")                                                                 \
    for (int i_ = 0; i_ < 4; ++i_) {                                                  \
      const unsigned char* sp_ = gsrc_[i_] + (t) * 128 + (p) * 16;                    \
      if (inA_[i_])                                                                   \
        __builtin_amdgcn_global_load_lds(                                             \
            (const __attribute__((address_space(1))) uint32_t*)sp_,                   \
            (__attribute__((address_space(3))) uint32_t*)(&LA[ldso_[i_]]), 16, 0, 0); \
      else                                                                            \
        __builtin_amdgcn_global_load_lds(                                             \
            (const __attribute__((address_space(1))) uint32_t*)sp_,                   \
            (__attribute__((address_space(3))) uint32_t*)(&LB[ldso_[i_]]), 16, 0, 0); \
    }                                                                                 \
  } while (0)

#define COMPUTE_MX(LAX, LBX, LAY, LBY) do {                                           \
    i32x8 Af_[5], Bf_[3];                                                             \
    _Pragma("unroll")                                                                 \
    for (int i_ = 0; i_ < 5; ++i_) {                                                  \
      i32x4v lo_ = *(const i32x4v*)&LAX[aoff_[i_]];                                   \
      i32x4v hi_ = *(const i32x4v*)&LAY[aoff_[i_]];                                   \
      Af_[i_] = __builtin_shufflevector(lo_, hi_, 0, 1, 2, 3, 4, 5, 6, 7);            \
    }                                                                                 \
    _Pragma("unroll")                                                                 \
    for (int j_ = 0; j_ < 3; ++j_) {                                                  \
      i32x4v lo_ = *(const i32x4v*)&LBX[boff_[j_]];                                   \
      i32x4v hi_ = *(const i32x4v*)&LBY[boff_[j_]];                                   \
      Bf_[j_] = __builtin_shufflevector(lo_, hi_, 0, 1, 2, 3, 4, 5, 6, 7);            \
    }                                                                                 \
    __builtin_amdgcn_s_setprio(1);                                                    \
    _Pragma("unroll")                                                                 \
    for (int i_ = 0; i_ < 5; ++i_)                                                    \
      _Pragma("unroll")                                                               \
      for (int j_ = 0; j_ < 3; ++j_)                                                  \
        acc[i_][j_] = __builtin_amdgcn_mfma_scale_f32_16x16x128_f8f6f4(               \
            Af_[i_], Bf_[j_], acc[i_][j_], 0, 0, 0, SC1, 0, SC1);                     \
    __builtin_amdgcn_s_setprio(0);                                                    \
  } while (0)

// counted-vmcnt wait + raw barrier; memory clobber + sched fence (rule #18)
#define WAITV_BAR(N) do {                                              \
    asm volatile("s_waitcnt vmcnt(" #N ")" ::: "memory");              \
    __builtin_amdgcn_sched_barrier(0);                                 \
    __builtin_amdgcn_s_barrier();                                      \
    __builtin_amdgcn_sched_barrier(0);                                 \
  } while (0)

__global__ __launch_bounds__(256, 3) void fused_kernel(
    const unsigned char* __restrict__ A8, const unsigned char* __restrict__ B8,
    const float* __restrict__ H, float* __restrict__ parts,
    unsigned int* __restrict__ counter, float* __restrict__ out) {
  __shared__ unsigned char la0[BM * BK], la1[BM * BK], la2[BM * BK];
  __shared__ unsigned char lb0[BN * BK], lb1[BN * BK], lb2[BN * BK];
  __shared__ float red[16];
  __shared__ int lastflag;

  float* gemmbuf = parts;            // [0,6000)
  float* corrbuf = parts + NGEMM;    // [6000,7200)

  int bid = blockIdx.x;
  int tid = threadIdx.x;
  int w = tid >> 6, l = tid & 63;

  if (bid >= NGEMM) {
    // ========== corr path: 16 lanes per item, 16 items per block ==========
    int cb  = bid - NGEMM;                 // 0..1199
    int g   = l >> 4;                      // item-slot within wave, 0..3
    int c4  = l & 15;                      // channel-lane within item
    int gid = cb * 16 + w * 4 + g;         // 0..19199
    int b = gid / NN, n = gid % NN;
    int gi = n / NW, gj = n % NW;
    float x = gj * 8.0f + 4.0f, y = gi * 8.0f + 4.0f;
    const float* h = H + b * 9;
    float inv = 1.0f / (h[6] * x + h[7] * y + h[8]);
    float wx = (h[0] * x + h[1] * y + h[2]) * inv;
    float wy = (h[3] * x + h[4] * y + h[5]) * inv;

    const uint4 av = *(const uint4*)(A8 + (size_t)(b * NN + n) * NC + c4 * 16);

    float fy = fminf(fmaxf((wy - 4.0f) * 0.125f, -2.0f), (float)NH + 1.0f);
    float fx = fminf(fmaxf((wx - 4.0f) * 0.125f, -2.0f), (float)NW + 1.0f);
    int i0 = (int)floorf(fy), j0 = (int)floorf(fx);

    bool  val[4];
    float dot[4];
    #pragma unroll
    for (int c = 0; c < 4; ++c) {
      int im = i0 + (c >> 1), jm = j0 + (c & 1);
      float dx = wx - (jm * 8.0f + 4.0f);
      float dy = wy - (im * 8.0f + 4.0f);
      val[c] = (im >= 0) & (im < NH) & (jm >= 0) & (jm < NW) &
               (dx * dx + dy * dy <= THR2);
      int m = val[c] ? (im * NW + jm) : 0;
      const uint4 bv = *(const uint4*)(B8 + (size_t)(b * NN + m) * NC + c4 * 16);
      float s = 0.0f;
      s = dot16(av.x, bv.x, s);
      s = dot16(av.y, bv.y, s);
      s = dot16(av.z, bv.z, s);
      s = dot16(av.w, bv.w, s);
      dot[c] = s;
    }
    #pragma unroll
    for (int off = 8; off > 0; off >>= 1) {
      dot[0] += __shfl_xor(dot[0], off);
      dot[1] += __shfl_xor(dot[1], off);
      dot[2] += __shfl_xor(dot[2], off);
      dot[3] += __shfl_xor(dot[3], off);
    }
    float corr = 0.0f;
    #pragma unroll
    for (int c = 0; c < 4; ++c)
      if (val[c])
        corr += fmaxf(M_POS - dot[c], 0.0f) - fmaxf(dot[c] - M_NEG, 0.0f);
    if (c4 == 0) red[w * 4 + g] = corr;
    __syncthreads();
    if (tid == 0) {
      float s = 0.0f;
      #pragma unroll
      for (int i = 0; i < 16; ++i) s += red[i];
      corrbuf[cb] = s;
    }
  } else {
    // ================= GEMM path (R14 exact) =================
    int nb = (bid & 7) * 750 + (bid >> 3);
    int b = nb / 1500; int r = nb % 1500;
    int tn = r / 50, tm = r % 50;
    int n0 = tn * BM, m0 = tm * BN;
    int wr = w >> 1, wc = w & 1;

    const unsigned char* Ab = A8 + (size_t)b * NN * NC;
    const unsigned char* Bb = B8 + (size_t)b * NN * NC;

    bool inA_[4]; const unsigned char* gsrc_[4]; int ldso_[4];
    #pragma unroll
    for (int i = 0; i < 4; ++i) {
      int base = w * 256 + i * 64;
      int cid = base + l;
      if (base < 640) {
        int row = cid >> 2, col = cid & 3;
        int scol = col ^ ((row >> 1) & 3);
        inA_[i] = true;
        gsrc_[i] = Ab + (size_t)(n0 + row) * NC + scol * 32;
        ldso_[i] = base * 16;
      } else {
        int cid2 = cid - 640;
        int row = cid2 >> 2, col = cid2 & 3;
        int scol = col ^ ((row >> 1) & 3);
        inA_[i] = false;
        gsrc_[i] = Bb + (size_t)(m0 + row) * NC + scol * 32;
        ldso_[i] = (base - 640) * 16;
      }
    }
    int aoff_[5], boff_[3];
    {
      int g = l >> 4;
      #pragma unroll
      for (int i = 0; i < 5; ++i) {
        int ra = wr * 80 + i * 16 + (l & 15);
        aoff_[i] = ra * 64 + ((g ^ ((ra >> 1) & 3)) << 4);
      }
      #pragma unroll
      for (int j = 0; j < 3; ++j) {
        int rb = wc * 48 + j * 16 + (l & 15);
        boff_[j] = rb * 64 + ((g ^ ((rb >> 1) & 3)) << 4);
      }
    }

    f32x4 acc[5][3];
    #pragma unroll
    for (int i = 0; i < 5; ++i)
      #pragma unroll
      for (int j = 0; j < 3; ++j)
        acc[i][j] = (f32x4){0.f, 0.f, 0.f, 0.f};

    STAGE(0, 0, la0, lb0);                 // X0
    STAGE(0, 1, la1, lb1);                 // Y0
    STAGE(1, 0, la2, lb2);                 // X1
    WAITV_BAR(4);                          // X0,Y0 landed (X1 in flight)
    COMPUTE_MX(la0, lb0, la1, lb1);        // K 0..127
    WAITV_BAR(4);                          // barrier: la0/lb0 free for reuse
    STAGE(1, 1, la0, lb0);                 // Y1
    WAITV_BAR(0);                          // X1,Y1 landed
    COMPUTE_MX(la2, lb2, la0, lb0);        // K 128..255

    float lsum = 0.0f;
    #pragma unroll
    for (int i = 0; i < 5; ++i)
      #pragma unroll
      for (int j = 0; j < 3; ++j)
        #pragma unroll
        for (int q = 0; q < 4; ++q)
          lsum += fmaxf(acc[i][j][q] - M_NEG, 0.0f);

    #pragma unroll
    for (int off = 32; off > 0; off >>= 1)
      lsum += __shfl_xor(lsum, off);
    if (l == 0) red[w] = lsum;
    __syncthreads();
    if (tid == 0)
      gemmbuf[nb] = red[0] + red[1] + red[2] + red[3];
  }

  // ============ common tail: last block reduces all partials ============
  if (tid == 0) {
    __threadfence();                                   // publish partial store
    unsigned int t = atomicAdd(counter, 1u);
    lastflag = (t == (unsigned int)(NBLK - 1));
  }
  __syncthreads();
  if (lastflag) {
    __threadfence();                                   // acquire: see all partials
    float v = 0.0f;
    for (int i = tid; i < NPART; i += 256)
      v += parts[i];
    #pragma unroll
    for (int off = 32; off > 0; off >>= 1)
      v += __shfl_xor(v, off);
    __syncthreads();                                   // red[] reuse guard
    if (l == 0) red[w] = v;
    __syncthreads();
    if (tid == 0)
      out[0] = (red[0] + red[1] + red[2] + red[3]) *
               (1.0f / ((float)NB * (float)NN * (float)NN));
  }
}

extern "C" void kernel_launch(void* const* d_in, const int* in_sizes, int n_in,
                              void* d_out, int out_size, void* d_ws, size_t ws_size,
                              hipStream_t stream) {
  const float* da = (const float*)d_in[0];
  const float* db = (const float*)d_in[1];
  const float* H  = (const float*)d_in[2];
  // d_in[3] = valid_mask (all ones, unused by the reference math)

  char* ws = (char*)d_ws;
  float* parts = (float*)ws;                          // 7200 floats
  unsigned int* counter = (unsigned int*)(ws + CNT_OFF);
  unsigned char* A8 = (unsigned char*)(ws + A8_OFF);
  unsigned char* B8 = (unsigned char*)(ws + B8_OFF);

  hipMemsetAsync(counter, 0, 4, stream);
  t8_kernel<<<2400, 256, 0, stream>>>(da, db, A8, B8);
  fused_kernel<<<NBLK, 256, 0, stream>>>(A8, B8, H, parts, counter, (float*)d_out);
}

// Round 19
// 49.134 us; speedup vs baseline: 4.6532x; 4.6532x over previous
//
#include <hip/hip_runtime.h>
#include <stdint.h>

#define NB 4
#define NC 256
#define NH 60
#define NW 80
#define NN (NH*NW)   // 4800

#define M_POS 1.0f
#define M_NEG 0.2f
#define THR2  64.0f  // THRESHOLD^2

typedef __attribute__((ext_vector_type(4))) float f32x4;
typedef __attribute__((ext_vector_type(8))) int   i32x8;
typedef __attribute__((ext_vector_type(4))) int   i32x4v;

#define SC1 0x7F7F7F7F   // e8m0 scale bytes = 127 -> 2^0 = 1.0

// ws layout (bytes):
//      0 : gemmbuf[6000] float
//  24000 : corrbuf[1200] float     (contiguous: NPART = 7200 floats from 0)
// 102400 : A8 [B][N][C] fp8 e4m3   (4915200 B)
// 5017600: B8 [B][N][C] fp8 e4m3   (4915200 B)
#define CORR_OFF 24000
#define A8_OFF   102400
#define B8_OFF   5017600
#define NPART    7200

#define NGEMM 6000
#define NCORR 1200

// ---------------- transpose+convert [C][N] f32 -> [N][C] fp8 ----------------
__global__ void t8_kernel(const float* __restrict__ da, const float* __restrict__ db,
                          unsigned char* __restrict__ A8, unsigned char* __restrict__ B8) {
  int t = blockIdx.x;              // 0..2399 = 2 tensors * 4 b * 4 ct * 75 nt
  int tensor = t / 1200; int rem = t % 1200;
  int b  = rem / 300;    int rem2 = rem % 300;
  int ct = rem2 / 75,    nt = rem2 % 75;
  int c0 = ct * 64, n0 = nt * 64;
  const float* in = (tensor ? db : da) + ((size_t)b * NC + c0) * NN + n0;
  unsigned char* out = (tensor ? B8 : A8) + ((size_t)b * NN + n0) * NC + c0;

  __shared__ float tile[64][65];
  int tr = threadIdx.x >> 6, tc = threadIdx.x & 63;
  #pragma unroll
  for (int i = 0; i < 16; ++i) {
    int c = i * 4 + tr;
    tile[c][tc] = in[(size_t)c * NN + tc];
  }
  __syncthreads();
  // each thread: one n-row, 16 consecutive channels -> one uint4 store
  int n_loc = threadIdx.x >> 2;        // 0..63
  int cb    = (threadIdx.x & 3) * 16;  // 0,16,32,48
  uint32_t wv[4];
  #pragma unroll
  for (int q = 0; q < 4; ++q) {
    uint32_t r = 0;
    r = __builtin_amdgcn_cvt_pk_fp8_f32(tile[cb + q*4 + 0][n_loc], tile[cb + q*4 + 1][n_loc], r, 0);
    r = __builtin_amdgcn_cvt_pk_fp8_f32(tile[cb + q*4 + 2][n_loc], tile[cb + q*4 + 3][n_loc], r, 1);
    wv[q] = r;
  }
  uint4 pack = make_uint4(wv[0], wv[1], wv[2], wv[3]);
  *(uint4*)&out[(size_t)n_loc * NC + cb] = pack;
}

__device__ __forceinline__ float dot16(uint32_t a, uint32_t b, float acc) {
  acc += __builtin_amdgcn_cvt_f32_fp8(a, 0) * __builtin_amdgcn_cvt_f32_fp8(b, 0);
  acc += __builtin_amdgcn_cvt_f32_fp8(a, 1) * __builtin_amdgcn_cvt_f32_fp8(b, 1);
  acc += __builtin_amdgcn_cvt_f32_fp8(a, 2) * __builtin_amdgcn_cvt_f32_fp8(b, 2);
  acc += __builtin_amdgcn_cvt_f32_fp8(a, 3) * __builtin_amdgcn_cvt_f32_fp8(b, 3);
  return acc;
}

// ---------------- fused MX-fp8 GEMM(+hinge) + corr kernel ----------------
// blocks [0,6000): GEMM 160(n)x96(m), 4 waves 2x2, wave 80x48 = 5x3 frags.
//   K=256 as 2 pairs of K=128, staged K-interleaved by 16B-col parity
//   (R14-verified 0-conflict form). 3 buffer pairs, counted vmcnt. [R14 exact]
// blocks [6000,7200): sparse mask correction, 16 lanes per (b,n) item
//   (16 items/block): uint4 channel loads, 4-step in-group butterfly,
//   branchless 4-candidate ILP.
#define BM 160
#define BN 96
#define BK 64

// 1024 16B-chunks per stage: 0..639 = A (160 rows x 4 cols), 640..1023 = B (96x4)
// 4 global_load_lds per thread; linear LDS dest; source col = t*128 + scol*32 + p*16
#define STAGE(t, p, LA, LB) do {                                                      \
    _Pragma("unroll")                                                                 \
    for (int i_ = 0; i_ < 4; ++i_) {                                                  \
      const unsigned char* sp_ = gsrc_[i_] + (t) * 128 + (p) * 16;                    \
      if (inA_[i_])                                                                   \
        __builtin_amdgcn_global_load_lds(                                             \
            (const __attribute__((address_space(1))) uint32_t*)sp_,                   \
            (__attribute__((address_space(3))) uint32_t*)(&LA[ldso_[i_]]), 16, 0, 0); \
      else                                                                            \
        __builtin_amdgcn_global_load_lds(                                             \
            (const __attribute__((address_space(1))) uint32_t*)sp_,                   \
            (__attribute__((address_space(3))) uint32_t*)(&LB[ldso_[i_]]), 16, 0, 0); \
    }                                                                                 \
  } while (0)

// one K=128 MX pair: lo 16B from X buffers, hi 16B from Y buffers, same aoff.
// 16 x ds_read_b128 (all R10-form), 15 MX MFMAs.
#define COMPUTE_MX(LAX, LBX, LAY, LBY) do {                                           \
    i32x8 Af_[5], Bf_[3];                                                             \
    _Pragma("unroll")                                                                 \
    for (int i_ = 0; i_ < 5; ++i_) {                                                  \
      i32x4v lo_ = *(const i32x4v*)&LAX[aoff_[i_]];                                   \
      i32x4v hi_ = *(const i32x4v*)&LAY[aoff_[i_]];                                   \
      Af_[i_] = __builtin_shufflevector(lo_, hi_, 0, 1, 2, 3, 4, 5, 6, 7);            \
    }                                                                                 \
    _Pragma("unroll")                                                                 \
    for (int j_ = 0; j_ < 3; ++j_) {                                                  \
      i32x4v lo_ = *(const i32x4v*)&LBX[boff_[j_]];                                   \
      i32x4v hi_ = *(const i32x4v*)&LBY[boff_[j_]];                                   \
      Bf_[j_] = __builtin_shufflevector(lo_, hi_, 0, 1, 2, 3, 4, 5, 6, 7);            \
    }                                                                                 \
    __builtin_amdgcn_s_setprio(1);                                                    \
    _Pragma("unroll")                                                                 \
    for (int i_ = 0; i_ < 5; ++i_)                                                    \
      _Pragma("unroll")                                                               \
      for (int j_ = 0; j_ < 3; ++j_)                                                  \
        acc[i_][j_] = __builtin_amdgcn_mfma_scale_f32_16x16x128_f8f6f4(               \
            Af_[i_], Bf_[j_], acc[i_][j_], 0, 0, 0, SC1, 0, SC1);                     \
    __builtin_amdgcn_s_setprio(0);                                                    \
  } while (0)

// counted-vmcnt wait + raw barrier; memory clobber + sched fence (rule #18)
#define WAITV_BAR(N) do {                                              \
    asm volatile("s_waitcnt vmcnt(" #N ")" ::: "memory");              \
    __builtin_amdgcn_sched_barrier(0);                                 \
    __builtin_amdgcn_s_barrier();                                      \
    __builtin_amdgcn_sched_barrier(0);                                 \
  } while (0)

__global__ __launch_bounds__(256, 3) void fused_kernel(
    const unsigned char* __restrict__ A8, const unsigned char* __restrict__ B8,
    const float* __restrict__ H,
    float* __restrict__ gemmbuf, float* __restrict__ corrbuf) {
  __shared__ unsigned char la0[BM * BK], la1[BM * BK], la2[BM * BK];
  __shared__ unsigned char lb0[BN * BK], lb1[BN * BK], lb2[BN * BK];
  __shared__ float red[16];

  int bid = blockIdx.x;
  int tid = threadIdx.x;
  int w = tid >> 6, l = tid & 63;

  if (bid >= NGEMM) {
    // ========== corr path: 16 lanes per item, 16 items per block ==========
    int cb  = bid - NGEMM;                 // 0..1199
    int g   = l >> 4;                      // item-slot within wave, 0..3
    int c4  = l & 15;                      // channel-lane within item
    int gid = cb * 16 + w * 4 + g;         // 0..19199
    int b = gid / NN, n = gid % NN;
    int gi = n / NW, gj = n % NW;
    float x = gj * 8.0f + 4.0f, y = gi * 8.0f + 4.0f;
    const float* h = H + b * 9;
    float inv = 1.0f / (h[6] * x + h[7] * y + h[8]);
    float wx = (h[0] * x + h[1] * y + h[2]) * inv;
    float wy = (h[3] * x + h[4] * y + h[5]) * inv;

    const uint4 av = *(const uint4*)(A8 + (size_t)(b * NN + n) * NC + c4 * 16);

    float fy = fminf(fmaxf((wy - 4.0f) * 0.125f, -2.0f), (float)NH + 1.0f);
    float fx = fminf(fmaxf((wx - 4.0f) * 0.125f, -2.0f), (float)NW + 1.0f);
    int i0 = (int)floorf(fy), j0 = (int)floorf(fx);

    bool  val[4];
    float dot[4];
    #pragma unroll
    for (int c = 0; c < 4; ++c) {
      int im = i0 + (c >> 1), jm = j0 + (c & 1);
      float dx = wx - (jm * 8.0f + 4.0f);
      float dy = wy - (im * 8.0f + 4.0f);
      val[c] = (im >= 0) & (im < NH) & (jm >= 0) & (jm < NW) &
               (dx * dx + dy * dy <= THR2);
      int m = val[c] ? (im * NW + jm) : 0;
      const uint4 bv = *(const uint4*)(B8 + (size_t)(b * NN + m) * NC + c4 * 16);
      float s = 0.0f;
      s = dot16(av.x, bv.x, s);
      s = dot16(av.y, bv.y, s);
      s = dot16(av.z, bv.z, s);
      s = dot16(av.w, bv.w, s);
      dot[c] = s;
    }
    // 4-step butterfly within each 16-lane group, 4 candidates interleaved
    #pragma unroll
    for (int off = 8; off > 0; off >>= 1) {
      dot[0] += __shfl_xor(dot[0], off);
      dot[1] += __shfl_xor(dot[1], off);
      dot[2] += __shfl_xor(dot[2], off);
      dot[3] += __shfl_xor(dot[3], off);
    }
    float corr = 0.0f;
    #pragma unroll
    for (int c = 0; c < 4; ++c)
      if (val[c])
        corr += fmaxf(M_POS - dot[c], 0.0f) - fmaxf(dot[c] - M_NEG, 0.0f);
    if (c4 == 0) red[w * 4 + g] = corr;
    __syncthreads();
    if (tid == 0) {
      float s = 0.0f;
      #pragma unroll
      for (int i = 0; i < 16; ++i) s += red[i];
      corrbuf[cb] = s;
    }
    return;
  }

  // ================= GEMM path (R14 exact) =================
  // XCD-aware bijective swizzle over the 6000 gemm blocks
  int nb = (bid & 7) * 750 + (bid >> 3);
  int b = nb / 1500; int r = nb % 1500;
  int tn = r / 50, tm = r % 50;
  int n0 = tn * BM, m0 = tm * BN;
  int wr = w >> 1, wc = w & 1;

  const unsigned char* Ab = A8 + (size_t)b * NN * NC;
  const unsigned char* Bb = B8 + (size_t)b * NN * NC;

  // hoisted staging bases: row base + scol*32 (even-col position within the
  // K=128 window); STAGE adds t*128 + p*16.
  bool inA_[4]; const unsigned char* gsrc_[4]; int ldso_[4];
  #pragma unroll
  for (int i = 0; i < 4; ++i) {
    int base = w * 256 + i * 64;
    int cid = base + l;
    if (base < 640) {
      int row = cid >> 2, col = cid & 3;
      int scol = col ^ ((row >> 1) & 3);
      inA_[i] = true;
      gsrc_[i] = Ab + (size_t)(n0 + row) * NC + scol * 32;
      ldso_[i] = base * 16;
    } else {
      int cid2 = cid - 640;
      int row = cid2 >> 2, col = cid2 & 3;
      int scol = col ^ ((row >> 1) & 3);
      inA_[i] = false;
      gsrc_[i] = Bb + (size_t)(m0 + row) * NC + scol * 32;
      ldso_[i] = (base - 640) * 16;
    }
  }
  // hoisted LDS fragment byte-offsets: R10's exact proven form --
  // quarter g reads 16B col g ^ ((row>>1)&3); same offset in X and Y buffers.
  int aoff_[5], boff_[3];
  {
    int g = l >> 4;
    #pragma unroll
    for (int i = 0; i < 5; ++i) {
      int ra = wr * 80 + i * 16 + (l & 15);
      aoff_[i] = ra * 64 + ((g ^ ((ra >> 1) & 3)) << 4);
    }
    #pragma unroll
    for (int j = 0; j < 3; ++j) {
      int rb = wc * 48 + j * 16 + (l & 15);
      boff_[j] = rb * 64 + ((g ^ ((rb >> 1) & 3)) << 4);
    }
  }

  f32x4 acc[5][3];
  #pragma unroll
  for (int i = 0; i < 5; ++i)
    #pragma unroll
    for (int j = 0; j < 3; ++j)
      acc[i][j] = (f32x4){0.f, 0.f, 0.f, 0.f};

  // pipeline: X0,Y0,X1 staged, compute pair0, stage Y1, compute pair1
  STAGE(0, 0, la0, lb0);                 // X0
  STAGE(0, 1, la1, lb1);                 // Y0
  STAGE(1, 0, la2, lb2);                 // X1
  WAITV_BAR(4);                          // X0,Y0 landed (X1 in flight)
  COMPUTE_MX(la0, lb0, la1, lb1);        // K 0..127
  WAITV_BAR(4);                          // barrier: la0/lb0 free for reuse
  STAGE(1, 1, la0, lb0);                 // Y1
  WAITV_BAR(0);                          // X1,Y1 landed
  COMPUTE_MX(la2, lb2, la0, lb0);        // K 128..255

  // epilogue: negative-branch hinge only (mask handled by corr path)
  float lsum = 0.0f;
  #pragma unroll
  for (int i = 0; i < 5; ++i)
    #pragma unroll
    for (int j = 0; j < 3; ++j)
      #pragma unroll
      for (int q = 0; q < 4; ++q)
        lsum += fmaxf(acc[i][j][q] - M_NEG, 0.0f);

  #pragma unroll
  for (int off = 32; off > 0; off >>= 1)
    lsum += __shfl_xor(lsum, off);
  if (l == 0) red[w] = lsum;
  __syncthreads();
  if (tid == 0)
    gemmbuf[nb] = red[0] + red[1] + red[2] + red[3];
}

// ---------------- final reduction over all partials ----------------
__global__ void finalize_kernel(const float* __restrict__ parts, float* __restrict__ out) {
  float v = 0.0f;
  for (int i = threadIdx.x; i < NPART; i += 1024)
    v += parts[i];
  #pragma unroll
  for (int off = 32; off > 0; off >>= 1)
    v += __shfl_xor(v, off);
  __shared__ float red[16];
  if ((threadIdx.x & 63) == 0) red[threadIdx.x >> 6] = v;
  __syncthreads();
  if (threadIdx.x == 0) {
    float s = 0.0f;
    #pragma unroll
    for (int i = 0; i < 16; ++i) s += red[i];
    out[0] = s * (1.0f / ((float)NB * (float)NN * (float)NN));
  }
}

extern "C" void kernel_launch(void* const* d_in, const int* in_sizes, int n_in,
                              void* d_out, int out_size, void* d_ws, size_t ws_size,
                              hipStream_t stream) {
  const float* da = (const float*)d_in[0];
  const float* db = (const float*)d_in[1];
  const float* H  = (const float*)d_in[2];
  // d_in[3] = valid_mask (all ones, unused by the reference math)

  char* ws = (char*)d_ws;
  float* gemmbuf = (float*)ws;                    // 6000 floats
  float* corrbuf = (float*)(ws + CORR_OFF);       // 1200 floats, contiguous after
  unsigned char* A8 = (unsigned char*)(ws + A8_OFF);
  unsigned char* B8 = (unsigned char*)(ws + B8_OFF);

  t8_kernel<<<2400, 256, 0, stream>>>(da, db, A8, B8);
  fused_kernel<<<NGEMM + NCORR, 256, 0, stream>>>(A8, B8, H, gemmbuf, corrbuf);
  finalize_kernel<<<1, 1024, 0, stream>>>(gemmbuf, (float*)d_out);
}